// Round 24
// baseline (214.390 us; speedup 1.0000x reference)
//
#include <hip/hip_runtime.h>
#include <hip/hip_fp16.h>

#define NN 512
#define NH 256             // half row
#define NBLK 4             // blocks per matrix (sweeps)
#define BROWS 128          // rows per block (sweeps)
#define THREADS 512        // 8 waves (sweeps)
#define NWAVE 8
#define RPW 16             // rows per wave (sweeps)
#define NITER 10
// k_exp geometry (pure stream, full occupancy)
#define XGRID 2048
#define XTHR 256
#define XCPT 8             // chunks per thread (fully unrolled)
// k_final geometry
#define FBLK 16
#define FROWS 32
#define FTHR 256
#define FSTEP 8

typedef float fv4 __attribute__((ext_vector_type(4)));      // NT-compatible vec4
typedef uint32_t uv4 __attribute__((ext_vector_type(4)));
typedef uint32_t uv2 __attribute__((ext_vector_type(2)));

union H2U { uint32_t u; __half2 h; };

__device__ __forceinline__ float wave_reduce_sum(float v) {
    #pragma unroll
    for (int off = 32; off > 0; off >>= 1)
        v += __shfl_xor(v, off, 64);
    return v;   // all 64 lanes hold the sum
}

__device__ __forceinline__ uint4 pack8(const float e[8]) {
    H2U a, b, c, d;
    a.h = __floats2half2_rn(e[0], e[1]);
    b.h = __floats2half2_rn(e[2], e[3]);
    c.h = __floats2half2_rn(e[4], e[5]);
    d.h = __floats2half2_rn(e[6], e[7]);
    return make_uint4(a.u, b.u, c.u, d.u);
}

__device__ __forceinline__ void unpack8(uint4 q, float e[8]) {
    H2U u; float2 f;
    u.u = q.x; f = __half22float2(u.h); e[0] = f.x; e[1] = f.y;
    u.u = q.y; f = __half22float2(u.h); e[2] = f.x; e[3] = f.y;
    u.u = q.z; f = __half22float2(u.h); e[4] = f.x; e[5] = f.y;
    u.u = q.w; f = __half22float2(u.h); e[6] = f.x; e[7] = f.y;
}

// Manual e4m3-style codec (R20: gfx942 fp8 builtins SIGABRT on gfx950).
// E in [3.3e-3, 330]; clamp to [2^-6, 440]. Encode: round-half at 3-bit
// mantissa, (bits-(120<<23))>>20. Decode: bits = (code<<20) + (120<<23).
__device__ __forceinline__ uint32_t enc1_fp8(float x) {
    x = fminf(fmaxf(x, 0.015625f), 440.0f);
    uint32_t b = __float_as_uint(x);
    b += 0x00080000u;                       // round-half-up at bit 20
    return (b - 0x3C000000u) >> 20;         // 7-bit e4m3 code
}

__device__ __forceinline__ uv2 pack8_fp8(const float e[8]) {
    uint32_t w0 = enc1_fp8(e[0]) | (enc1_fp8(e[1]) << 8) |
                  (enc1_fp8(e[2]) << 16) | (enc1_fp8(e[3]) << 24);
    uint32_t w1 = enc1_fp8(e[4]) | (enc1_fp8(e[5]) << 8) |
                  (enc1_fp8(e[6]) << 16) | (enc1_fp8(e[7]) << 24);
    uv2 r = { w0, w1 };
    return r;
}

__device__ __forceinline__ void unpack8_fp8(uint2 q, float e[8]) {
    #pragma unroll
    for (int k = 0; k < 4; ++k)
        e[k] = __uint_as_float((((q.x >> (8 * k)) & 0xFFu) << 20) + 0x3C000000u);
    #pragma unroll
    for (int k = 0; k < 4; ++k)
        e[4 + k] = __uint_as_float((((q.y >> (8 * k)) & 0xFFu) << 20) + 0x3C000000u);
}

// Lane->column map: slot k<4 -> col lane*4+k, slot k>=4 -> col 256+lane*4+
// (k-4). Every global access is one contiguous 8-16B per lane.
//
// R23 synthesis (refined): kernels whose ONLY writes are NT run at ~6 TB/s
// combined (k_final: cached-read 96MB + NT-write 128MB in ~38us); kernels
// with CACHED writes are capped at 2.2-2.7 TB/s across all geometries.
// R24: k_exp = pure stream (cached S read; NT store E16+E8; no phase 2 --
// R22's confound was reading NT data in-kernel). Sweep0 moves to its own
// k_sweep<FIRST> dispatch; t=1's read-allocate makes E8 L3-hot for t>=2.
// Cached L3 footprint = S(128)+E8(32) < 256MB -> S stays L3-resident
// across graph replays.

__global__ __launch_bounds__(XTHR)
void k_exp(const float* __restrict__ S, uint32_t* __restrict__ E32,
           uint32_t* __restrict__ E8) {
    const size_t t0 = (size_t)blockIdx.x * XTHR + threadIdx.x;
    const size_t stride = (size_t)XGRID * XTHR;   // 524288 threads
    #pragma unroll
    for (int k = 0; k < XCPT; ++k) {
        const size_t idx = t0 + (size_t)k * stride;   // 16B chunk index
        const size_t row = idx >> 6;
        const int ln = (int)(idx & 63);
        const float* rp = S + row * NN;
        float4 q0 = *reinterpret_cast<const float4*>(rp + ln * 4);
        float4 q1 = *reinterpret_cast<const float4*>(rp + NH + ln * 4);
        float e[8];
        e[0] = __expf(q0.x); e[1] = __expf(q0.y); e[2] = __expf(q0.z); e[3] = __expf(q0.w);
        e[4] = __expf(q1.x); e[5] = __expf(q1.y); e[6] = __expf(q1.z); e[7] = __expf(q1.w);
        uint4 p16v = pack8(e);
        uv4 pv = { p16v.x, p16v.y, p16v.z, p16v.w };
        __builtin_nontemporal_store(pv, reinterpret_cast<uv4*>(E32 + idx * 4));
        __builtin_nontemporal_store(pack8_fp8(e), reinterpret_cast<uv2*>(E8 + idx * 2));
    }
}

template<int NPART, bool FIRST>
__global__ __launch_bounds__(THREADS)
void k_sweep(const uint32_t* __restrict__ E8,
             const float* __restrict__ pr, float* __restrict__ pw,
             float* __restrict__ A, int nmat) {
    const int m = blockIdx.x % nmat, blk = blockIdx.x / nmat;
    const int tid = threadIdx.x, lane = tid & 63, w = tid >> 6;
    __shared__ float Bsh[NN];
    __shared__ float part[NWAVE][NN];

    float b[8];
    if constexpr (FIRST) {
        #pragma unroll
        for (int k = 0; k < 8; ++k) b[k] = 1.0f;
    } else {
        {   // B head: complete previous col sums (fixed order, deterministic)
            float s = 0.f;
            #pragma unroll
            for (int k = 0; k < NPART; ++k) s += pr[((size_t)m * NPART + k) * NN + tid];
            Bsh[tid] = 1.0f / s;
        }
        __syncthreads();
        float4 b0 = *reinterpret_cast<float4*>(&Bsh[lane * 4]);
        float4 b1 = *reinterpret_cast<float4*>(&Bsh[NH + lane * 4]);
        b[0]=b0.x; b[1]=b0.y; b[2]=b0.z; b[3]=b0.w;
        b[4]=b1.x; b[5]=b1.y; b[6]=b1.z; b[7]=b1.w;
    }
    float c[8] = {0.f,0.f,0.f,0.f,0.f,0.f,0.f,0.f};

    #pragma unroll 4
    for (int r = 0; r < RPW; ++r) {
        const size_t row = (size_t)m * NN + blk * BROWS + w * RPW + r;
        float e[8];
        unpack8_fp8(*reinterpret_cast<const uint2*>(E8 + row * (NN / 4) + lane * 2), e);
        float d = ((e[0]*b[0]+e[1]*b[1]) + (e[2]*b[2]+e[3]*b[3])) +
                  ((e[4]*b[4]+e[5]*b[5]) + (e[6]*b[6]+e[7]*b[7]));
        d = wave_reduce_sum(d);
        const float a = 1.0f / d;
        if (lane == 0) A[row] = a;
        #pragma unroll
        for (int k = 0; k < 8; ++k) c[k] += e[k] * a;
    }
    *reinterpret_cast<float4*>(&part[w][lane * 4])      = make_float4(c[0],c[1],c[2],c[3]);
    *reinterpret_cast<float4*>(&part[w][NH + lane * 4]) = make_float4(c[4],c[5],c[6],c[7]);
    __syncthreads();
    {
        float s2 = 0.f;
        #pragma unroll
        for (int k = 0; k < NWAVE; ++k) s2 += part[k][tid];
        pw[((size_t)m * NBLK + blk) * NN + tid] = s2;
    }
}

__global__ __launch_bounds__(FTHR)
void k_final(const uint32_t* __restrict__ E32,
             const float* __restrict__ pr, const float* __restrict__ A,
             float* __restrict__ out, int nmat) {
    const int m = blockIdx.x >> 4, blk = blockIdx.x & 15;
    const int tid = threadIdx.x, lane = tid & 63;
    __shared__ float Bsh[NN];

    {   // B head: 2 columns per thread
        #pragma unroll
        for (int h = 0; h < 2; ++h) {
            const int j = h * FTHR + tid;
            float s = 0.f;
            #pragma unroll
            for (int k = 0; k < NBLK; ++k) s += pr[((size_t)m * NBLK + k) * NN + j];
            Bsh[j] = 1.0f / s;
        }
    }
    __syncthreads();

    float b[8];
    {
        float4 b0 = *reinterpret_cast<float4*>(&Bsh[lane * 4]);
        float4 b1 = *reinterpret_cast<float4*>(&Bsh[NH + lane * 4]);
        b[0]=b0.x; b[1]=b0.y; b[2]=b0.z; b[3]=b0.w;
        b[4]=b1.x; b[5]=b1.y; b[6]=b1.z; b[7]=b1.w;
    }

    const size_t row0 = (size_t)m * NN + (size_t)blk * FROWS;
    #pragma unroll 4
    for (int s = 0; s < FSTEP; ++s) {
        const int chunk = s * FTHR + tid;          // wave-uniform row per step
        const size_t row = row0 + (chunk >> 6);
        const int ln = chunk & 63;
        const float a = A[row];                    // wave-uniform broadcast
        float e[8];
        unpack8(*reinterpret_cast<const uint4*>(E32 + row * (NN / 2) + ln * 4), e);
        float* op = out + row * NN;
        fv4 o0 = { e[0]*a*b[0], e[1]*a*b[1], e[2]*a*b[2], e[3]*a*b[3] };
        fv4 o1 = { e[4]*a*b[4], e[5]*a*b[5], e[6]*a*b[6], e[7]*a*b[7] };
        __builtin_nontemporal_store(o0, reinterpret_cast<fv4*>(op + ln * 4));
        __builtin_nontemporal_store(o1, reinterpret_cast<fv4*>(op + NH + ln * 4));
    }
}

// ---------------- fallback (small ws): recompute exp, multi-kernel ----
__device__ __forceinline__ void load_row8_s(const float* __restrict__ S,
                                            size_t row_g, int lane, float e[8]) {
    float4 q0 = *reinterpret_cast<const float4*>(S + row_g * NN + lane * 4);
    float4 q1 = *reinterpret_cast<const float4*>(S + row_g * NN + NH + lane * 4);
    e[0] = __expf(q0.x); e[1] = __expf(q0.y); e[2] = __expf(q0.z); e[3] = __expf(q0.w);
    e[4] = __expf(q1.x); e[5] = __expf(q1.y); e[6] = __expf(q1.z); e[7] = __expf(q1.w);
}

template<bool FIRST>
__global__ __launch_bounds__(THREADS)
void k_sweep_nf(const float* __restrict__ S, const float* __restrict__ pr,
                float* __restrict__ pw, float* __restrict__ A, int nmat) {
    const int m = blockIdx.x % nmat, blk = blockIdx.x / nmat;
    const int tid = threadIdx.x, lane = tid & 63, w = tid >> 6;
    __shared__ float Bsh[NN];
    __shared__ float part[NWAVE][NN];

    if constexpr (!FIRST) {
        float s = 0.f;
        #pragma unroll
        for (int k = 0; k < NBLK; ++k) s += pr[((size_t)m * NBLK + k) * NN + tid];
        Bsh[tid] = 1.0f / s;
        __syncthreads();
    }
    float b[8];
    if constexpr (FIRST) {
        #pragma unroll
        for (int k = 0; k < 8; ++k) b[k] = 1.0f;
    } else {
        float4 b0 = *reinterpret_cast<float4*>(&Bsh[lane * 4]);
        float4 b1 = *reinterpret_cast<float4*>(&Bsh[NH + lane * 4]);
        b[0]=b0.x; b[1]=b0.y; b[2]=b0.z; b[3]=b0.w;
        b[4]=b1.x; b[5]=b1.y; b[6]=b1.z; b[7]=b1.w;
    }
    float c[8] = {0.f,0.f,0.f,0.f,0.f,0.f,0.f,0.f};
    #pragma unroll 4
    for (int r = 0; r < RPW; ++r) {
        const size_t row_g = (size_t)m * NN + blk * BROWS + w * RPW + r;
        float e[8];
        load_row8_s(S, row_g, lane, e);
        float d = ((e[0]*b[0]+e[1]*b[1])+(e[2]*b[2]+e[3]*b[3])) +
                  ((e[4]*b[4]+e[5]*b[5])+(e[6]*b[6]+e[7]*b[7]));
        d = wave_reduce_sum(d);
        const float a = 1.0f / d;
        if (lane == 0) A[row_g] = a;
        #pragma unroll
        for (int k = 0; k < 8; ++k) c[k] += e[k] * a;
    }
    *reinterpret_cast<float4*>(&part[w][lane * 4])      = make_float4(c[0],c[1],c[2],c[3]);
    *reinterpret_cast<float4*>(&part[w][NH + lane * 4]) = make_float4(c[4],c[5],c[6],c[7]);
    __syncthreads();
    {
        float s2 = 0.f;
        #pragma unroll
        for (int k = 0; k < NWAVE; ++k) s2 += part[k][tid];
        pw[((size_t)m * NBLK + blk) * NN + tid] = s2;
    }
}

__global__ __launch_bounds__(THREADS)
void k_final_nf(const float* __restrict__ S, const float* __restrict__ pr,
                const float* __restrict__ A, float* __restrict__ out, int nmat) {
    const int m = blockIdx.x % nmat, blk = blockIdx.x / nmat;
    const int tid = threadIdx.x, lane = tid & 63, w = tid >> 6;
    __shared__ float Bsh[NN];
    {
        float s = 0.f;
        #pragma unroll
        for (int k = 0; k < NBLK; ++k) s += pr[((size_t)m * NBLK + k) * NN + tid];
        Bsh[tid] = 1.0f / s;
    }
    __syncthreads();
    float b[8];
    {
        float4 b0 = *reinterpret_cast<float4*>(&Bsh[lane * 4]);
        float4 b1 = *reinterpret_cast<float4*>(&Bsh[NH + lane * 4]);
        b[0]=b0.x; b[1]=b0.y; b[2]=b0.z; b[3]=b0.w;
        b[4]=b1.x; b[5]=b1.y; b[6]=b1.z; b[7]=b1.w;
    }
    #pragma unroll 4
    for (int r = 0; r < RPW; ++r) {
        const size_t row_g = (size_t)m * NN + blk * BROWS + w * RPW + r;
        const float a = A[row_g];
        float e[8];
        load_row8_s(S, row_g, lane, e);
        *reinterpret_cast<float4*>(out + row_g * NN + lane * 4) =
            make_float4(e[0]*a*b[0], e[1]*a*b[1], e[2]*a*b[2], e[3]*a*b[3]);
        *reinterpret_cast<float4*>(out + row_g * NN + NH + lane * 4) =
            make_float4(e[4]*a*b[4], e[5]*a*b[5], e[6]*a*b[6], e[7]*a*b[7]);
    }
}

extern "C" void kernel_launch(void* const* d_in, const int* in_sizes, int n_in,
                              void* d_out, int out_size, void* d_ws, size_t ws_size,
                              hipStream_t stream) {
    const float* S = reinterpret_cast<const float*>(d_in[0]);
    float* out = reinterpret_cast<float*>(d_out);
    const int nmat = in_sizes[0] / (NN * NN);   // 128 for (8,16,512,512)

    const size_t e16_bytes  = (size_t)in_sizes[0] * 2;            // fp16 E
    const size_t e8_bytes   = (size_t)in_sizes[0];                // fp8 E
    const size_t pa_floats  = (size_t)nmat * NBLK * NN;           // sweep partials
    const size_t a_floats   = (size_t)nmat * NN;
    const size_t need = e16_bytes + e8_bytes + (2 * pa_floats + a_floats) * 4;

    if (d_ws != nullptr && ws_size >= need) {
        char* wsb = reinterpret_cast<char*>(d_ws);
        uint32_t* E32 = reinterpret_cast<uint32_t*>(wsb);
        uint32_t* E8  = reinterpret_cast<uint32_t*>(wsb + e16_bytes);
        float* p0  = reinterpret_cast<float*>(wsb + e16_bytes + e8_bytes);
        float* p1  = p0 + pa_floats;
        float* A   = p1 + pa_floats;
        float* bufs[2] = { p0, p1 };

        dim3 gs(nmat * NBLK), bs(THREADS);
        k_exp<<<dim3(XGRID), dim3(XTHR), 0, stream>>>(S, E32, E8);
        k_sweep<NBLK, true><<<gs, bs, 0, stream>>>(E8, nullptr, p0, A, nmat);   // t=0 -> p0
        for (int t = 1; t < NITER; ++t)                                         // t=1..9
            k_sweep<NBLK, false><<<gs, bs, 0, stream>>>(E8, bufs[1 - (t & 1)],
                                                        bufs[t & 1], A, nmat);
        // t=9 wrote bufs[9&1] = p1
        k_final<<<dim3(nmat * FBLK), dim3(FTHR), 0, stream>>>(E32, p1, A, out, nmat);
    } else {
        float* p0 = reinterpret_cast<float*>(d_ws);
        float* p1 = p0 + pa_floats;
        float* A  = p1 + pa_floats;
        dim3 g(nmat * NBLK), b(THREADS);
        k_sweep_nf<true><<<g, b, 0, stream>>>(S, nullptr, p0, A, nmat);
        for (int t = 1; t < NITER; ++t)
            k_sweep_nf<false><<<g, b, 0, stream>>>(S, (t & 1) ? p0 : p1,
                                                   (t & 1) ? p1 : p0, A, nmat);
        k_final_nf<<<g, b, 0, stream>>>(S, p1, A, out, nmat);
    }
}

// Round 25
// 196.399 us; speedup vs baseline: 1.0916x; 1.0916x over previous
//
#include <hip/hip_runtime.h>
#include <hip/hip_fp16.h>

#define NN 512
#define NH 256             // half row
#define NBLK 4             // blocks per matrix (sweeps)
#define BROWS 128          // rows per block (sweeps)
#define THREADS 512        // 8 waves (sweeps)
#define NWAVE 8
#define RPW 16             // rows per wave (sweeps)
#define NITER 10
// k_exp0 geometry (full-occupancy: 2048 blocks x 256 thr, 32 rows/block)
#define XBLK 16            // blocks per matrix
#define XROWS 32           // rows per block
#define XTHR 256           // 4 waves
#define XWAVE 4
#define XRPW 8             // rows per wave (sweep0 phase)
#define XCPT 8             // exp chunks per thread (XROWS*64/XTHR)
// k_final geometry
#define FBLK 16
#define FROWS 32
#define FTHR 256
#define FSTEP 8

typedef float fv4 __attribute__((ext_vector_type(4)));      // NT-compatible vec4

union H2U { uint32_t u; __half2 h; };

__device__ __forceinline__ float wave_reduce_sum(float v) {
    #pragma unroll
    for (int off = 32; off > 0; off >>= 1)
        v += __shfl_xor(v, off, 64);
    return v;   // all 64 lanes hold the sum
}

// Manual e4m3-style codec (R20: gfx942 fp8 builtins SIGABRT on gfx950).
// E in [3.3e-3, 330]; clamp to [2^-6, 440]. Encode: round-half at 3-bit
// mantissa, (bits-(120<<23))>>20. Decode: bits = (code<<20) + (120<<23).
__device__ __forceinline__ uint32_t enc1_fp8(float x) {
    x = fminf(fmaxf(x, 0.015625f), 440.0f);
    uint32_t b = __float_as_uint(x);
    b += 0x00080000u;                       // round-half-up at bit 20
    return (b - 0x3C000000u) >> 20;         // 7-bit e4m3 code
}

__device__ __forceinline__ uint2 pack8_fp8(const float e[8]) {
    uint32_t w0 = enc1_fp8(e[0]) | (enc1_fp8(e[1]) << 8) |
                  (enc1_fp8(e[2]) << 16) | (enc1_fp8(e[3]) << 24);
    uint32_t w1 = enc1_fp8(e[4]) | (enc1_fp8(e[5]) << 8) |
                  (enc1_fp8(e[6]) << 16) | (enc1_fp8(e[7]) << 24);
    return make_uint2(w0, w1);
}

__device__ __forceinline__ void unpack8_fp8(uint2 q, float e[8]) {
    #pragma unroll
    for (int k = 0; k < 4; ++k)
        e[k] = __uint_as_float((((q.x >> (8 * k)) & 0xFFu) << 20) + 0x3C000000u);
    #pragma unroll
    for (int k = 0; k < 4; ++k)
        e[4 + k] = __uint_as_float((((q.y >> (8 * k)) & 0xFFu) << 20) + 0x3C000000u);
}

// Lane->column map: slot k<4 -> col lane*4+k, slot k>=4 -> col 256+lane*4+
// (k-4). Every global access is one contiguous 8-16B per lane.
//
// R24 falsified "NT-writes-only => 6 TB/s": ANY S-reading kernel is capped
// ~2.3-2.5 TB/s (12+ configs). R25: reduce bytes UNDER the cap -- drop E16
// entirely. k_exp0 (R23's fused structure) writes only E8 (34 MB, cached);
// k_final recomputes exp(S) in fp32 from S, which stays L3-resident
// (cached footprint = S 128 + E8 32 < 256 MB; out is NT). Output precision
// improves (fp32 E); trajectory identical to R23 (all-fp8 sweeps).

__global__ __launch_bounds__(XTHR)
void k_exp0(const float* __restrict__ S, uint32_t* __restrict__ E8,
            float* __restrict__ A, float* __restrict__ p16, int nmat) {
    const int m = blockIdx.x % nmat, blk = blockIdx.x / nmat;
    const int tid = threadIdx.x, lane = tid & 63, w = tid >> 6;
    __shared__ float part[XWAVE][NN];

    const size_t row0 = (size_t)m * NN + (size_t)blk * XROWS;

    // ---- phase 1: stream exp(S) -> E8 (cached store) for own 32 rows ----
    #pragma unroll 4
    for (int s = 0; s < XCPT; ++s) {
        const int chunk = s * XTHR + tid;      // 0..2047
        const size_t row = row0 + (chunk >> 6);
        const int ln = chunk & 63;
        const float* rp = S + row * NN;
        float4 q0 = *reinterpret_cast<const float4*>(rp + ln * 4);
        float4 q1 = *reinterpret_cast<const float4*>(rp + NH + ln * 4);
        float e[8];
        e[0] = __expf(q0.x); e[1] = __expf(q0.y); e[2] = __expf(q0.z); e[3] = __expf(q0.w);
        e[4] = __expf(q1.x); e[5] = __expf(q1.y); e[6] = __expf(q1.z); e[7] = __expf(q1.w);
        *reinterpret_cast<uint2*>(E8 + row * (NN / 4) + ln * 2) = pack8_fp8(e);
    }
    __syncthreads();   // own E8 rows visible block-locally

    // ---- phase 2: sweep0 (B = 1) reading own E8 back (L2-hot) ----
    float c[8] = {0.f, 0.f, 0.f, 0.f, 0.f, 0.f, 0.f, 0.f};
    #pragma unroll 4
    for (int r = 0; r < XRPW; ++r) {
        const size_t row = row0 + w * XRPW + r;
        float e[8];
        unpack8_fp8(*reinterpret_cast<const uint2*>(E8 + row * (NN / 4) + lane * 2), e);
        float d = ((e[0]+e[1]) + (e[2]+e[3])) + ((e[4]+e[5]) + (e[6]+e[7]));
        d = wave_reduce_sum(d);
        const float a = 1.0f / d;
        if (lane == 0) A[row] = a;
        #pragma unroll
        for (int k = 0; k < 8; ++k) c[k] += e[k] * a;
    }
    *reinterpret_cast<float4*>(&part[w][lane * 4])      = make_float4(c[0], c[1], c[2], c[3]);
    *reinterpret_cast<float4*>(&part[w][NH + lane * 4]) = make_float4(c[4], c[5], c[6], c[7]);
    __syncthreads();
    #pragma unroll
    for (int h = 0; h < 2; ++h) {
        const int j = h * XTHR + tid;
        float s2 = (part[0][j] + part[1][j]) + (part[2][j] + part[3][j]);
        p16[((size_t)m * XBLK + blk) * NN + j] = s2;
    }
}

template<int NPART>
__global__ __launch_bounds__(THREADS)
void k_sweep(const uint32_t* __restrict__ E8,
             const float* __restrict__ pr, float* __restrict__ pw,
             float* __restrict__ A, int nmat) {
    const int m = blockIdx.x % nmat, blk = blockIdx.x / nmat;
    const int tid = threadIdx.x, lane = tid & 63, w = tid >> 6;
    __shared__ float Bsh[NN];
    __shared__ float part[NWAVE][NN];

    {   // B head: complete previous col sums (fixed order, deterministic)
        float s = 0.f;
        #pragma unroll
        for (int k = 0; k < NPART; ++k) s += pr[((size_t)m * NPART + k) * NN + tid];
        Bsh[tid] = 1.0f / s;
    }
    __syncthreads();

    float b[8];
    {
        float4 b0 = *reinterpret_cast<float4*>(&Bsh[lane * 4]);
        float4 b1 = *reinterpret_cast<float4*>(&Bsh[NH + lane * 4]);
        b[0]=b0.x; b[1]=b0.y; b[2]=b0.z; b[3]=b0.w;
        b[4]=b1.x; b[5]=b1.y; b[6]=b1.z; b[7]=b1.w;
    }
    float c[8] = {0.f,0.f,0.f,0.f,0.f,0.f,0.f,0.f};

    #pragma unroll 4
    for (int r = 0; r < RPW; ++r) {
        const size_t row = (size_t)m * NN + blk * BROWS + w * RPW + r;
        float e[8];
        unpack8_fp8(*reinterpret_cast<const uint2*>(E8 + row * (NN / 4) + lane * 2), e);
        float d = ((e[0]*b[0]+e[1]*b[1]) + (e[2]*b[2]+e[3]*b[3])) +
                  ((e[4]*b[4]+e[5]*b[5]) + (e[6]*b[6]+e[7]*b[7]));
        d = wave_reduce_sum(d);
        const float a = 1.0f / d;
        if (lane == 0) A[row] = a;
        #pragma unroll
        for (int k = 0; k < 8; ++k) c[k] += e[k] * a;
    }
    *reinterpret_cast<float4*>(&part[w][lane * 4])      = make_float4(c[0],c[1],c[2],c[3]);
    *reinterpret_cast<float4*>(&part[w][NH + lane * 4]) = make_float4(c[4],c[5],c[6],c[7]);
    __syncthreads();
    {
        float s2 = 0.f;
        #pragma unroll
        for (int k = 0; k < NWAVE; ++k) s2 += part[k][tid];
        pw[((size_t)m * NBLK + blk) * NN + tid] = s2;
    }
}

__global__ __launch_bounds__(FTHR)
void k_final(const float* __restrict__ S,
             const float* __restrict__ pr, const float* __restrict__ A,
             float* __restrict__ out, int nmat) {
    const int m = blockIdx.x >> 4, blk = blockIdx.x & 15;
    const int tid = threadIdx.x, lane = tid & 63;
    __shared__ float Bsh[NN];

    {   // B head: 2 columns per thread
        #pragma unroll
        for (int h = 0; h < 2; ++h) {
            const int j = h * FTHR + tid;
            float s = 0.f;
            #pragma unroll
            for (int k = 0; k < NBLK; ++k) s += pr[((size_t)m * NBLK + k) * NN + j];
            Bsh[j] = 1.0f / s;
        }
    }
    __syncthreads();

    float b[8];
    {
        float4 b0 = *reinterpret_cast<float4*>(&Bsh[lane * 4]);
        float4 b1 = *reinterpret_cast<float4*>(&Bsh[NH + lane * 4]);
        b[0]=b0.x; b[1]=b0.y; b[2]=b0.z; b[3]=b0.w;
        b[4]=b1.x; b[5]=b1.y; b[6]=b1.z; b[7]=b1.w;
    }

    const size_t row0 = (size_t)m * NN + (size_t)blk * FROWS;
    #pragma unroll 4
    for (int s = 0; s < FSTEP; ++s) {
        const int chunk = s * FTHR + tid;          // wave-uniform row per step
        const size_t row = row0 + (chunk >> 6);
        const int ln = chunk & 63;
        const float a = A[row];                    // wave-uniform broadcast
        const float* rp = S + row * NN;            // S is L3-resident
        float4 q0 = *reinterpret_cast<const float4*>(rp + ln * 4);
        float4 q1 = *reinterpret_cast<const float4*>(rp + NH + ln * 4);
        float* op = out + row * NN;
        fv4 o0 = { __expf(q0.x)*a*b[0], __expf(q0.y)*a*b[1],
                   __expf(q0.z)*a*b[2], __expf(q0.w)*a*b[3] };
        fv4 o1 = { __expf(q1.x)*a*b[4], __expf(q1.y)*a*b[5],
                   __expf(q1.z)*a*b[6], __expf(q1.w)*a*b[7] };
        __builtin_nontemporal_store(o0, reinterpret_cast<fv4*>(op + ln * 4));
        __builtin_nontemporal_store(o1, reinterpret_cast<fv4*>(op + NH + ln * 4));
    }
}

// ---------------- fallback (small ws): recompute exp, multi-kernel ----
__device__ __forceinline__ void load_row8_s(const float* __restrict__ S,
                                            size_t row_g, int lane, float e[8]) {
    float4 q0 = *reinterpret_cast<const float4*>(S + row_g * NN + lane * 4);
    float4 q1 = *reinterpret_cast<const float4*>(S + row_g * NN + NH + lane * 4);
    e[0] = __expf(q0.x); e[1] = __expf(q0.y); e[2] = __expf(q0.z); e[3] = __expf(q0.w);
    e[4] = __expf(q1.x); e[5] = __expf(q1.y); e[6] = __expf(q1.z); e[7] = __expf(q1.w);
}

template<bool FIRST>
__global__ __launch_bounds__(THREADS)
void k_sweep_nf(const float* __restrict__ S, const float* __restrict__ pr,
                float* __restrict__ pw, float* __restrict__ A, int nmat) {
    const int m = blockIdx.x % nmat, blk = blockIdx.x / nmat;
    const int tid = threadIdx.x, lane = tid & 63, w = tid >> 6;
    __shared__ float Bsh[NN];
    __shared__ float part[NWAVE][NN];

    if constexpr (!FIRST) {
        float s = 0.f;
        #pragma unroll
        for (int k = 0; k < NBLK; ++k) s += pr[((size_t)m * NBLK + k) * NN + tid];
        Bsh[tid] = 1.0f / s;
        __syncthreads();
    }
    float b[8];
    if constexpr (FIRST) {
        #pragma unroll
        for (int k = 0; k < 8; ++k) b[k] = 1.0f;
    } else {
        float4 b0 = *reinterpret_cast<float4*>(&Bsh[lane * 4]);
        float4 b1 = *reinterpret_cast<float4*>(&Bsh[NH + lane * 4]);
        b[0]=b0.x; b[1]=b0.y; b[2]=b0.z; b[3]=b0.w;
        b[4]=b1.x; b[5]=b1.y; b[6]=b1.z; b[7]=b1.w;
    }
    float c[8] = {0.f,0.f,0.f,0.f,0.f,0.f,0.f,0.f};
    #pragma unroll 4
    for (int r = 0; r < RPW; ++r) {
        const size_t row_g = (size_t)m * NN + blk * BROWS + w * RPW + r;
        float e[8];
        load_row8_s(S, row_g, lane, e);
        float d = ((e[0]*b[0]+e[1]*b[1])+(e[2]*b[2]+e[3]*b[3])) +
                  ((e[4]*b[4]+e[5]*b[5])+(e[6]*b[6]+e[7]*b[7]));
        d = wave_reduce_sum(d);
        const float a = 1.0f / d;
        if (lane == 0) A[row_g] = a;
        #pragma unroll
        for (int k = 0; k < 8; ++k) c[k] += e[k] * a;
    }
    *reinterpret_cast<float4*>(&part[w][lane * 4])      = make_float4(c[0],c[1],c[2],c[3]);
    *reinterpret_cast<float4*>(&part[w][NH + lane * 4]) = make_float4(c[4],c[5],c[6],c[7]);
    __syncthreads();
    {
        float s2 = 0.f;
        #pragma unroll
        for (int k = 0; k < NWAVE; ++k) s2 += part[k][tid];
        pw[((size_t)m * NBLK + blk) * NN + tid] = s2;
    }
}

__global__ __launch_bounds__(THREADS)
void k_final_nf(const float* __restrict__ S, const float* __restrict__ pr,
                const float* __restrict__ A, float* __restrict__ out, int nmat) {
    const int m = blockIdx.x % nmat, blk = blockIdx.x / nmat;
    const int tid = threadIdx.x, lane = tid & 63, w = tid >> 6;
    __shared__ float Bsh[NN];
    {
        float s = 0.f;
        #pragma unroll
        for (int k = 0; k < NBLK; ++k) s += pr[((size_t)m * NBLK + k) * NN + tid];
        Bsh[tid] = 1.0f / s;
    }
    __syncthreads();
    float b[8];
    {
        float4 b0 = *reinterpret_cast<float4*>(&Bsh[lane * 4]);
        float4 b1 = *reinterpret_cast<float4*>(&Bsh[NH + lane * 4]);
        b[0]=b0.x; b[1]=b0.y; b[2]=b0.z; b[3]=b0.w;
        b[4]=b1.x; b[5]=b1.y; b[6]=b1.z; b[7]=b1.w;
    }
    #pragma unroll 4
    for (int r = 0; r < RPW; ++r) {
        const size_t row_g = (size_t)m * NN + blk * BROWS + w * RPW + r;
        const float a = A[row_g];
        float e[8];
        load_row8_s(S, row_g, lane, e);
        *reinterpret_cast<float4*>(out + row_g * NN + lane * 4) =
            make_float4(e[0]*a*b[0], e[1]*a*b[1], e[2]*a*b[2], e[3]*a*b[3]);
        *reinterpret_cast<float4*>(out + row_g * NN + NH + lane * 4) =
            make_float4(e[4]*a*b[4], e[5]*a*b[5], e[6]*a*b[6], e[7]*a*b[7]);
    }
}

extern "C" void kernel_launch(void* const* d_in, const int* in_sizes, int n_in,
                              void* d_out, int out_size, void* d_ws, size_t ws_size,
                              hipStream_t stream) {
    const float* S = reinterpret_cast<const float*>(d_in[0]);
    float* out = reinterpret_cast<float*>(d_out);
    const int nmat = in_sizes[0] / (NN * NN);   // 128 for (8,16,512,512)

    const size_t e8_bytes   = (size_t)in_sizes[0];                // fp8 E
    const size_t p16_floats = (size_t)nmat * XBLK * NN;           // sweep0 partials
    const size_t pa_floats  = (size_t)nmat * NBLK * NN;           // sweep partials
    const size_t a_floats   = (size_t)nmat * NN;
    const size_t need = e8_bytes + (p16_floats + 2 * pa_floats + a_floats) * 4;

    if (d_ws != nullptr && ws_size >= need) {
        char* wsb = reinterpret_cast<char*>(d_ws);
        uint32_t* E8 = reinterpret_cast<uint32_t*>(wsb);
        float* p16 = reinterpret_cast<float*>(wsb + e8_bytes);
        float* p0  = p16 + p16_floats;
        float* p1  = p0 + pa_floats;
        float* A   = p1 + pa_floats;
        float* bufs[2] = { p0, p1 };

        dim3 gs(nmat * NBLK), bs(THREADS);
        k_exp0<<<dim3(nmat * XBLK), dim3(XTHR), 0, stream>>>(S, E8, A, p16, nmat);
        k_sweep<XBLK><<<gs, bs, 0, stream>>>(E8, p16, p0, A, nmat);          // t=1
        for (int t = 2; t < NITER; ++t)                                      // t=2..9
            k_sweep<NBLK><<<gs, bs, 0, stream>>>(E8, bufs[t & 1],
                                                 bufs[1 - (t & 1)], A, nmat);
        // t=9 wrote bufs[1-(9&1)] = bufs[0] = p0
        k_final<<<dim3(nmat * FBLK), dim3(FTHR), 0, stream>>>(S, p0, A, out, nmat);
    } else {
        float* p0 = reinterpret_cast<float*>(d_ws);
        float* p1 = p0 + pa_floats;
        float* A  = p1 + pa_floats;
        dim3 g(nmat * NBLK), b(THREADS);
        k_sweep_nf<true><<<g, b, 0, stream>>>(S, nullptr, p0, A, nmat);
        for (int t = 1; t < NITER; ++t)
            k_sweep_nf<false><<<g, b, 0, stream>>>(S, (t & 1) ? p0 : p1,
                                                   (t & 1) ? p1 : p0, A, nmat);
        k_final_nf<<<g, b, 0, stream>>>(S, p1, A, out, nmat);
    }
}